// Round 3
// baseline (232.025 us; speedup 1.0000x reference)
//
#include <hip/hip_runtime.h>
#include <math.h>

#define MM 4096
#define DD 2048

// ws layout (floats):
// [0..M)    qt
// [M..2M)   k (scaled by 1/sqrt(M))
// [2M..3M)  v
// [3M+0] it, [3M+1] ft, [3M+2] ot, [3M+3] denom
// [4M..5M)  num (per-row C@qt numerator)

// ---------------- K1: qt/k/v GEMVs + gate scalars ----------------
// blocks 0..1023: 4 waves each, one row-triple per wave (x staged in LDS)
// blocks 1024..1026: gate dots (double accumulation)
__global__ __launch_bounds__(256) void k1_gemv_gates(
    const float* __restrict__ x,
    const float* __restrict__ Wq, const float* __restrict__ bq,
    const float* __restrict__ Wk, const float* __restrict__ bk,
    const float* __restrict__ Wv, const float* __restrict__ bV,
    const float* __restrict__ Wi, const float* __restrict__ bi,
    const float* __restrict__ Wf, const float* __restrict__ bf,
    const float* __restrict__ Wo, const float* __restrict__ bo,
    float* __restrict__ ws)
{
    const int lane = threadIdx.x & 63;
    const int wid  = threadIdx.x >> 6;

    if (blockIdx.x >= 1024) {
        // ----- gate blocks: double-precision dot over D -----
        __shared__ double gred[4];
        const int g = blockIdx.x - 1024;           // 0=i, 1=f, 2=o
        const float* G = (g == 0) ? Wi : ((g == 1) ? Wf : Wo);
        const float4* g4 = (const float4*)G;
        const float4* xv = (const float4*)x;
        double acc = 0.0;
        for (int t = threadIdx.x; t < DD / 4; t += 256) {
            float4 gg = g4[t];
            float4 xx = xv[t];
            acc += (double)gg.x * xx.x + (double)gg.y * xx.y
                 + (double)gg.z * xx.z + (double)gg.w * xx.w;
        }
        for (int off = 32; off; off >>= 1) acc += __shfl_down(acc, off, 64);
        if (lane == 0) gred[wid] = acc;
        __syncthreads();
        if (threadIdx.x == 0) {
            double s = gred[0] + gred[1] + gred[2] + gred[3];
            if (g == 0)      ws[3 * MM + 0] = (float)exp(s + (double)bi[0]);
            else if (g == 1) ws[3 * MM + 1] = (float)exp(s + (double)bf[0]);
            else             ws[3 * MM + 2] = (float)(1.0 / (1.0 + exp(-(s + (double)bo[0]))));
        }
        return;
    }

    // ----- row blocks -----
    __shared__ float xs[DD];
    {
        const float4* xv  = (const float4*)x;
        float4*       xsv = (float4*)xs;
        xsv[threadIdx.x]       = xv[threadIdx.x];
        xsv[256 + threadIdx.x] = xv[256 + threadIdx.x];
    }
    __syncthreads();

    const int row = blockIdx.x * 4 + wid;
    const float4* wq = (const float4*)(Wq + (size_t)row * DD);
    const float4* wk = (const float4*)(Wk + (size_t)row * DD);
    const float4* wv = (const float4*)(Wv + (size_t)row * DD);

    float4 rq[8], rk[8], rv[8];
    #pragma unroll
    for (int t = 0; t < 8; ++t) rq[t] = wq[lane + 64 * t];
    #pragma unroll
    for (int t = 0; t < 8; ++t) rk[t] = wk[lane + 64 * t];
    #pragma unroll
    for (int t = 0; t < 8; ++t) rv[t] = wv[lane + 64 * t];

    const float4* xs4 = (const float4*)xs;
    float aq = 0.f, ak = 0.f, av = 0.f;
    #pragma unroll
    for (int t = 0; t < 8; ++t) {
        float4 xx = xs4[lane + 64 * t];
        aq += rq[t].x * xx.x + rq[t].y * xx.y + rq[t].z * xx.z + rq[t].w * xx.w;
        ak += rk[t].x * xx.x + rk[t].y * xx.y + rk[t].z * xx.z + rk[t].w * xx.w;
        av += rv[t].x * xx.x + rv[t].y * xx.y + rv[t].z * xx.z + rv[t].w * xx.w;
    }
    for (int off = 32; off; off >>= 1) {
        aq += __shfl_down(aq, off, 64);
        ak += __shfl_down(ak, off, 64);
        av += __shfl_down(av, off, 64);
    }
    if (lane == 0) {
        ws[row]          = aq + bq[row];
        ws[MM + row]     = (ak + bk[row]) * (1.0f / 64.0f);  // 1/sqrt(4096)
        ws[2 * MM + row] = av + bV[row];
    }
}

// ---------------- K2: C = ft*cp + it*outer(v,k); num = C@qt; block0: n & denom ----------------
__global__ __launch_bounds__(256) void k2_rowC(
    const float* __restrict__ cp, const float* __restrict__ n_prev,
    float* __restrict__ ws, float* __restrict__ C_out, float* __restrict__ n_out)
{
    __shared__ float ks[MM];
    __shared__ float qs[MM];
    __shared__ float sred[16];
    const int lane = threadIdx.x & 63;
    const int wid  = threadIdx.x >> 6;

    const float it = ws[3 * MM + 0];
    const float ft = ws[3 * MM + 1];

    if (blockIdx.x == 0) {
        // prelude: n = ft*n_prev + it*k ; denom = max(|n.qt|, 1)
        const float4* np4 = (const float4*)n_prev;
        const float4* kv4 = (const float4*)(ws + MM);
        const float4* qv4 = (const float4*)ws;
        float4* n4 = (float4*)n_out;
        float acc = 0.f;
        #pragma unroll
        for (int j = 0; j < MM / 4 / 256; ++j) {   // 4 iters
            int t = threadIdx.x + 256 * j;
            float4 np = np4[t], kk = kv4[t], qq = qv4[t];
            float4 nn;
            nn.x = fmaf(ft, np.x, it * kk.x);
            nn.y = fmaf(ft, np.y, it * kk.y);
            nn.z = fmaf(ft, np.z, it * kk.z);
            nn.w = fmaf(ft, np.w, it * kk.w);
            n4[t] = nn;
            acc += nn.x * qq.x + nn.y * qq.y + nn.z * qq.z + nn.w * qq.w;
        }
        for (int off = 32; off; off >>= 1) acc += __shfl_down(acc, off, 64);
        if (lane == 0) sred[wid] = acc;
        __syncthreads();
        if (threadIdx.x == 0) {
            float s = sred[0] + sred[1] + sred[2] + sred[3];
            ws[3 * MM + 3] = fmaxf(fabsf(s), 1.0f);
        }
        __syncthreads();
    }

    // stage k and qt in LDS (32 KB)
    {
        const float4* kv4 = (const float4*)(ws + MM);
        const float4* qv4 = (const float4*)ws;
        float4* ks4 = (float4*)ks;
        float4* qs4 = (float4*)qs;
        #pragma unroll
        for (int j = 0; j < MM / 4 / 256; ++j) {   // 4 each
            int t = threadIdx.x + 256 * j;
            ks4[t] = kv4[t];
            qs4[t] = qv4[t];
        }
    }
    __syncthreads();

    const float4* ks4 = (const float4*)ks;
    const float4* qs4 = (const float4*)qs;
    float rowacc[4];
    #pragma unroll
    for (int j = 0; j < 4; ++j) {                  // 4 rows per block
        const int row = blockIdx.x * 4 + j;
        const float ivi = it * ws[2 * MM + row];
        const float4* cprow = (const float4*)(cp + (size_t)row * MM);
        float4*       crow  = (float4*)(C_out + (size_t)row * MM);
        float acc = 0.f;
        #pragma unroll
        for (int u = 0; u < MM / 4 / 256; ++u) {   // 4 iters
            int t = threadIdx.x + 256 * u;
            float4 c = cprow[t], kk = ks4[t], qq = qs4[t];
            float4 o;
            o.x = fmaf(ivi, kk.x, ft * c.x);
            o.y = fmaf(ivi, kk.y, ft * c.y);
            o.z = fmaf(ivi, kk.z, ft * c.z);
            o.w = fmaf(ivi, kk.w, ft * c.w);
            crow[t] = o;
            acc += o.x * qq.x + o.y * qq.y + o.z * qq.z + o.w * qq.w;
        }
        rowacc[j] = acc;
    }
    __syncthreads();   // sred reuse safe (block 0)
    #pragma unroll
    for (int j = 0; j < 4; ++j) {
        float acc = rowacc[j];
        for (int off = 32; off; off >>= 1) acc += __shfl_down(acc, off, 64);
        if (lane == 0) sred[j * 4 + wid] = acc;
    }
    __syncthreads();
    if (threadIdx.x < 4) {
        int j = threadIdx.x;
        float s = sred[j * 4 + 0] + sred[j * 4 + 1] + sred[j * 4 + 2] + sred[j * 4 + 3];
        ws[4 * MM + blockIdx.x * 4 + j] = s;       // numerator
    }
}

// ---------------- K3: ht = ot * num / denom ----------------
__global__ __launch_bounds__(256) void k3_finalize(
    const float* __restrict__ ws, float* __restrict__ ht_out)
{
    const float ot    = ws[3 * MM + 2];
    const float denom = ws[3 * MM + 3];
    const int i = blockIdx.x * 256 + threadIdx.x;
    ht_out[i] = ot * (ws[4 * MM + i] / denom);
}

extern "C" void kernel_launch(void* const* d_in, const int* in_sizes, int n_in,
                              void* d_out, int out_size, void* d_ws, size_t ws_size,
                              hipStream_t stream)
{
    const float* x      = (const float*)d_in[0];
    const float* cp     = (const float*)d_in[1];
    const float* n_prev = (const float*)d_in[2];
    const float* Wq = (const float*)d_in[3];
    const float* bq = (const float*)d_in[4];
    const float* Wk = (const float*)d_in[5];
    const float* bk = (const float*)d_in[6];
    const float* Wv = (const float*)d_in[7];
    const float* bV = (const float*)d_in[8];
    const float* Wi = (const float*)d_in[9];
    const float* bi = (const float*)d_in[10];
    const float* Wf = (const float*)d_in[11];
    const float* bf = (const float*)d_in[12];
    const float* Wo = (const float*)d_in[13];
    const float* bo = (const float*)d_in[14];

    float* out = (float*)d_out;
    float* ht  = out;                        // (M,1)
    float* C   = out + MM;                   // (M,M)
    float* n   = out + MM + (size_t)MM * MM; // (M,1)
    float* ws  = (float*)d_ws;

    k1_gemv_gates<<<1027, 256, 0, stream>>>(x, Wq, bq, Wk, bk, Wv, bV,
                                            Wi, bi, Wf, bf, Wo, bo, ws);
    k2_rowC      <<<1024, 256, 0, stream>>>(cp, n_prev, ws, C, n);
    k3_finalize  <<<MM / 256, 256, 0, stream>>>(ws, ht);
}

// Round 4
// 229.640 us; speedup vs baseline: 1.0104x; 1.0104x over previous
//
#include <hip/hip_runtime.h>
#include <math.h>

#define MM 4096
#define DD 2048

typedef float floatx4 __attribute__((ext_vector_type(4)));

// ws layout (floats):
// [0..M)    qt
// [M..2M)   k (scaled by 1/sqrt(M))
// [2M..3M)  v
// [3M+0] it, [3M+1] ft, [3M+2] ot, [3M+3] denom
// [4M..5M)  num (per-row C@qt numerator)

// ---------------- K1: qt/k/v GEMVs + gate scalars ----------------
__global__ __launch_bounds__(256) void k1_gemv_gates(
    const float* __restrict__ x,
    const float* __restrict__ Wq, const float* __restrict__ bq,
    const float* __restrict__ Wk, const float* __restrict__ bk,
    const float* __restrict__ Wv, const float* __restrict__ bV,
    const float* __restrict__ Wi, const float* __restrict__ bi,
    const float* __restrict__ Wf, const float* __restrict__ bf,
    const float* __restrict__ Wo, const float* __restrict__ bo,
    float* __restrict__ ws)
{
    const int lane = threadIdx.x & 63;
    const int wid  = threadIdx.x >> 6;

    if (blockIdx.x >= 1024) {
        // ----- gate blocks: double-precision dot over D -----
        __shared__ double gred[4];
        const int g = blockIdx.x - 1024;           // 0=i, 1=f, 2=o
        const float* G = (g == 0) ? Wi : ((g == 1) ? Wf : Wo);
        const float4* g4 = (const float4*)G;
        const float4* xv = (const float4*)x;
        double acc = 0.0;
        for (int t = threadIdx.x; t < DD / 4; t += 256) {
            float4 gg = g4[t];
            float4 xx = xv[t];
            acc += (double)gg.x * xx.x + (double)gg.y * xx.y
                 + (double)gg.z * xx.z + (double)gg.w * xx.w;
        }
        for (int off = 32; off; off >>= 1) acc += __shfl_down(acc, off, 64);
        if (lane == 0) gred[wid] = acc;
        __syncthreads();
        if (threadIdx.x == 0) {
            double s = gred[0] + gred[1] + gred[2] + gred[3];
            if (g == 0)      ws[3 * MM + 0] = (float)exp(s + (double)bi[0]);
            else if (g == 1) ws[3 * MM + 1] = (float)exp(s + (double)bf[0]);
            else             ws[3 * MM + 2] = (float)(1.0 / (1.0 + exp(-(s + (double)bo[0]))));
        }
        return;
    }

    // ----- row blocks: 4 waves, one row-triple per wave, x staged in LDS -----
    __shared__ float xs[DD];
    {
        const float4* xv  = (const float4*)x;
        float4*       xsv = (float4*)xs;
        xsv[threadIdx.x]       = xv[threadIdx.x];
        xsv[256 + threadIdx.x] = xv[256 + threadIdx.x];
    }
    __syncthreads();

    const int row = blockIdx.x * 4 + wid;
    const float4* wq = (const float4*)(Wq + (size_t)row * DD);
    const float4* wk = (const float4*)(Wk + (size_t)row * DD);
    const float4* wv = (const float4*)(Wv + (size_t)row * DD);

    float4 rq[8], rk[8], rv[8];
    #pragma unroll
    for (int t = 0; t < 8; ++t) rq[t] = wq[lane + 64 * t];
    #pragma unroll
    for (int t = 0; t < 8; ++t) rk[t] = wk[lane + 64 * t];
    #pragma unroll
    for (int t = 0; t < 8; ++t) rv[t] = wv[lane + 64 * t];

    const float4* xs4 = (const float4*)xs;
    float aq = 0.f, ak = 0.f, av = 0.f;
    #pragma unroll
    for (int t = 0; t < 8; ++t) {
        float4 xx = xs4[lane + 64 * t];
        aq += rq[t].x * xx.x + rq[t].y * xx.y + rq[t].z * xx.z + rq[t].w * xx.w;
        ak += rk[t].x * xx.x + rk[t].y * xx.y + rk[t].z * xx.z + rk[t].w * xx.w;
        av += rv[t].x * xx.x + rv[t].y * xx.y + rv[t].z * xx.z + rv[t].w * xx.w;
    }
    for (int off = 32; off; off >>= 1) {
        aq += __shfl_down(aq, off, 64);
        ak += __shfl_down(ak, off, 64);
        av += __shfl_down(av, off, 64);
    }
    if (lane == 0) {
        ws[row]          = aq + bq[row];
        ws[MM + row]     = (ak + bk[row]) * (1.0f / 64.0f);  // 1/sqrt(4096)
        ws[2 * MM + row] = av + bV[row];
    }
}

// ---------------- K2: one row per block; extra block does n & denom ----------------
__global__ __launch_bounds__(256) void k2_rowC(
    const float* __restrict__ cp, const float* __restrict__ n_prev,
    float* __restrict__ ws, float* __restrict__ C_out, float* __restrict__ n_out)
{
    const int lane = threadIdx.x & 63;
    const int wid  = threadIdx.x >> 6;

    if (blockIdx.x == MM) {
        // prelude block: n = ft*n_prev + it*k ; denom = max(|n.qt|, 1)
        __shared__ float pred[4];
        const float it = ws[3 * MM + 0];
        const float ft = ws[3 * MM + 1];
        const float4* np4 = (const float4*)n_prev;
        const float4* kv4 = (const float4*)(ws + MM);
        const float4* qv4 = (const float4*)ws;
        float4* n4 = (float4*)n_out;
        float acc = 0.f;
        #pragma unroll
        for (int u = 0; u < 4; ++u) {
            int t = threadIdx.x + 256 * u;
            float4 np = np4[t], kk = kv4[t], qq = qv4[t];
            float4 nn;
            nn.x = fmaf(ft, np.x, it * kk.x);
            nn.y = fmaf(ft, np.y, it * kk.y);
            nn.z = fmaf(ft, np.z, it * kk.z);
            nn.w = fmaf(ft, np.w, it * kk.w);
            n4[t] = nn;
            acc += nn.x * qq.x + nn.y * qq.y + nn.z * qq.z + nn.w * qq.w;
        }
        for (int off = 32; off; off >>= 1) acc += __shfl_down(acc, off, 64);
        if (lane == 0) pred[wid] = acc;
        __syncthreads();
        if (threadIdx.x == 0) {
            float s = pred[0] + pred[1] + pred[2] + pred[3];
            ws[3 * MM + 3] = fmaxf(fabsf(s), 1.0f);
        }
        return;
    }

    // ----- row block -----
    __shared__ float sred[4];
    const int row = blockIdx.x;
    const float it  = ws[3 * MM + 0];
    const float ft  = ws[3 * MM + 1];
    const float ivi = it * ws[2 * MM + row];

    const float4* cprow = (const float4*)(cp + (size_t)row * MM);
    const float4* kv4   = (const float4*)(ws + MM);
    const float4* qv4   = (const float4*)ws;
    float4*       crow  = (float4*)(C_out + (size_t)row * MM);

    // issue ALL loads up front (12 independent dwordx4 per thread in flight)
    float4 c[4], kk[4], qq[4];
    #pragma unroll
    for (int u = 0; u < 4; ++u) c[u]  = cprow[threadIdx.x + 256 * u];
    #pragma unroll
    for (int u = 0; u < 4; ++u) kk[u] = kv4[threadIdx.x + 256 * u];
    #pragma unroll
    for (int u = 0; u < 4; ++u) qq[u] = qv4[threadIdx.x + 256 * u];

    float acc = 0.f;
    #pragma unroll
    for (int u = 0; u < 4; ++u) {
        float4 o;
        o.x = fmaf(ivi, kk[u].x, ft * c[u].x);
        o.y = fmaf(ivi, kk[u].y, ft * c[u].y);
        o.z = fmaf(ivi, kk[u].z, ft * c[u].z);
        o.w = fmaf(ivi, kk[u].w, ft * c[u].w);
        floatx4 ov = { o.x, o.y, o.z, o.w };
        __builtin_nontemporal_store(ov, (floatx4*)(crow + threadIdx.x + 256 * u));
        acc += o.x * qq[u].x + o.y * qq[u].y + o.z * qq[u].z + o.w * qq[u].w;
    }
    for (int off = 32; off; off >>= 1) acc += __shfl_down(acc, off, 64);
    if (lane == 0) sred[wid] = acc;
    __syncthreads();
    if (threadIdx.x == 0)
        ws[4 * MM + row] = sred[0] + sred[1] + sred[2] + sred[3];
}

// ---------------- K3: ht = ot * num / denom ----------------
__global__ __launch_bounds__(256) void k3_finalize(
    const float* __restrict__ ws, float* __restrict__ ht_out)
{
    const float ot    = ws[3 * MM + 2];
    const float denom = ws[3 * MM + 3];
    const int i = blockIdx.x * 256 + threadIdx.x;
    ht_out[i] = ot * (ws[4 * MM + i] / denom);
}

extern "C" void kernel_launch(void* const* d_in, const int* in_sizes, int n_in,
                              void* d_out, int out_size, void* d_ws, size_t ws_size,
                              hipStream_t stream)
{
    const float* x      = (const float*)d_in[0];
    const float* cp     = (const float*)d_in[1];
    const float* n_prev = (const float*)d_in[2];
    const float* Wq = (const float*)d_in[3];
    const float* bq = (const float*)d_in[4];
    const float* Wk = (const float*)d_in[5];
    const float* bk = (const float*)d_in[6];
    const float* Wv = (const float*)d_in[7];
    const float* bV = (const float*)d_in[8];
    const float* Wi = (const float*)d_in[9];
    const float* bi = (const float*)d_in[10];
    const float* Wf = (const float*)d_in[11];
    const float* bf = (const float*)d_in[12];
    const float* Wo = (const float*)d_in[13];
    const float* bo = (const float*)d_in[14];

    float* out = (float*)d_out;
    float* ht  = out;                        // (M,1)
    float* C   = out + MM;                   // (M,M)
    float* n   = out + MM + (size_t)MM * MM; // (M,1)
    float* ws  = (float*)d_ws;

    k1_gemv_gates<<<1027, 256, 0, stream>>>(x, Wq, bq, Wk, bk, Wv, bV,
                                            Wi, bi, Wf, bf, Wo, bo, ws);
    k2_rowC      <<<MM + 1, 256, 0, stream>>>(cp, n_prev, ws, C, n);
    k3_finalize  <<<MM / 256, 256, 0, stream>>>(ws, ht);
}

// Round 5
// 225.450 us; speedup vs baseline: 1.0292x; 1.0186x over previous
//
#include <hip/hip_runtime.h>
#include <math.h>

#define MM 4096
#define DD 2048
#define CHUNK 1024            // floats per row-chunk staged per wave (4 KB)

typedef float floatx4 __attribute__((ext_vector_type(4)));

// ws layout (floats):
// [0..M)    qt
// [M..2M)   k (scaled by 1/sqrt(M))
// [2M..3M)  v
// [3M+0] it, [3M+1] ft, [3M+2] ot, [3M+3] denom
// [4M..5M)  num (per-row C@qt numerator)

__device__ __forceinline__ void async_copy_1k(const float* src, float* lds_dst, int lane)
{
    // one wave: 64 lanes x 16 B = 1 KB, LDS dest = uniform base + lane*16
    __builtin_amdgcn_global_load_lds(
        (const __attribute__((address_space(1))) void*)(src + lane * 4),
        (__attribute__((address_space(3))) void*)lds_dst,
        16, 0, 0);
}

// ---------------- K1: qt/k/v GEMVs (async LDS staging) + gate scalars ----------------
__global__ __launch_bounds__(256) void k1_gemv_gates(
    const float* __restrict__ x,
    const float* __restrict__ Wq, const float* __restrict__ bq,
    const float* __restrict__ Wk, const float* __restrict__ bk,
    const float* __restrict__ Wv, const float* __restrict__ bV,
    const float* __restrict__ Wi, const float* __restrict__ bi,
    const float* __restrict__ Wf, const float* __restrict__ bf,
    const float* __restrict__ Wo, const float* __restrict__ bo,
    float* __restrict__ ws)
{
    const int lane = threadIdx.x & 63;
    const int wid  = threadIdx.x >> 6;

    if (blockIdx.x >= 1024) {
        // ----- gate blocks: double-precision dot over D -----
        __shared__ double gred[4];
        const int g = blockIdx.x - 1024;           // 0=i, 1=f, 2=o
        const float* G = (g == 0) ? Wi : ((g == 1) ? Wf : Wo);
        const float4* g4 = (const float4*)G;
        const float4* xv = (const float4*)x;
        double acc = 0.0;
        for (int t = threadIdx.x; t < DD / 4; t += 256) {
            float4 gg = g4[t];
            float4 xx = xv[t];
            acc += (double)gg.x * xx.x + (double)gg.y * xx.y
                 + (double)gg.z * xx.z + (double)gg.w * xx.w;
        }
        for (int off = 32; off; off >>= 1) acc += __shfl_down(acc, off, 64);
        if (lane == 0) gred[wid] = acc;
        __syncthreads();
        if (threadIdx.x == 0) {
            double s = gred[0] + gred[1] + gred[2] + gred[3];
            if (g == 0)      ws[3 * MM + 0] = (float)exp(s + (double)bi[0]);
            else if (g == 1) ws[3 * MM + 1] = (float)exp(s + (double)bf[0]);
            else             ws[3 * MM + 2] = (float)(1.0 / (1.0 + exp(-(s + (double)bo[0]))));
        }
        return;
    }

    // ----- row blocks: 4 waves, one row-triple per wave -----
    __shared__ float xs[DD];                 // 8 KB
    __shared__ float wbuf[4][3][CHUNK];      // 48 KB: per-wave q/k/v chunk staging

    {   // stage x (plain stores; visible after first barrier)
        const float4* xv  = (const float4*)x;
        float4*       xsv = (float4*)xs;
        xsv[threadIdx.x]       = xv[threadIdx.x];
        xsv[256 + threadIdx.x] = xv[256 + threadIdx.x];
    }

    const int row = blockIdx.x * 4 + wid;
    const float* wqrow = Wq + (size_t)row * DD;
    const float* wkrow = Wk + (size_t)row * DD;
    const float* wvrow = Wv + (size_t)row * DD;

    float aq = 0.f, ak = 0.f, av = 0.f;

    #pragma unroll
    for (int h = 0; h < DD / CHUNK; ++h) {   // 2 chunks
        // queue 12 KB of async DMA per wave (zero VGPR cost)
        #pragma unroll
        for (int c = 0; c < CHUNK / 256; ++c) {   // 4 x 1 KB per row
            async_copy_1k(wqrow + h * CHUNK + c * 256, &wbuf[wid][0][c * 256], lane);
            async_copy_1k(wkrow + h * CHUNK + c * 256, &wbuf[wid][1][c * 256], lane);
            async_copy_1k(wvrow + h * CHUNK + c * 256, &wbuf[wid][2][c * 256], lane);
        }
        __syncthreads();   // drains vmcnt -> DMA data landed; xs visible (h=0)

        const float4* xs4 = (const float4*)(xs + h * CHUNK);
        const float4* q4  = (const float4*)wbuf[wid][0];
        const float4* k4  = (const float4*)wbuf[wid][1];
        const float4* v4  = (const float4*)wbuf[wid][2];
        #pragma unroll
        for (int t = 0; t < CHUNK / 4 / 64; ++t) {   // 4 iters
            float4 xx = xs4[lane + 64 * t];
            float4 qq = q4 [lane + 64 * t];
            float4 kk = k4 [lane + 64 * t];
            float4 vv = v4 [lane + 64 * t];
            aq += qq.x * xx.x + qq.y * xx.y + qq.z * xx.z + qq.w * xx.w;
            ak += kk.x * xx.x + kk.y * xx.y + kk.z * xx.z + kk.w * xx.w;
            av += vv.x * xx.x + vv.y * xx.y + vv.z * xx.z + vv.w * xx.w;
        }
        __syncthreads();   // protect wbuf reuse by next chunk's DMA
    }

    for (int off = 32; off; off >>= 1) {
        aq += __shfl_down(aq, off, 64);
        ak += __shfl_down(ak, off, 64);
        av += __shfl_down(av, off, 64);
    }
    if (lane == 0) {
        ws[row]          = aq + bq[row];
        ws[MM + row]     = (ak + bk[row]) * (1.0f / 64.0f);  // 1/sqrt(4096)
        ws[2 * MM + row] = av + bV[row];
    }
}

// ---------------- K2: one row per block; extra block does n & denom ----------------
__global__ __launch_bounds__(256) void k2_rowC(
    const float* __restrict__ cp, const float* __restrict__ n_prev,
    float* __restrict__ ws, float* __restrict__ C_out, float* __restrict__ n_out)
{
    const int lane = threadIdx.x & 63;
    const int wid  = threadIdx.x >> 6;

    if (blockIdx.x == MM) {
        __shared__ float pred[4];
        const float it = ws[3 * MM + 0];
        const float ft = ws[3 * MM + 1];
        const float4* np4 = (const float4*)n_prev;
        const float4* kv4 = (const float4*)(ws + MM);
        const float4* qv4 = (const float4*)ws;
        float4* n4 = (float4*)n_out;
        float acc = 0.f;
        #pragma unroll
        for (int u = 0; u < 4; ++u) {
            int t = threadIdx.x + 256 * u;
            float4 np = np4[t], kk = kv4[t], qq = qv4[t];
            float4 nn;
            nn.x = fmaf(ft, np.x, it * kk.x);
            nn.y = fmaf(ft, np.y, it * kk.y);
            nn.z = fmaf(ft, np.z, it * kk.z);
            nn.w = fmaf(ft, np.w, it * kk.w);
            n4[t] = nn;
            acc += nn.x * qq.x + nn.y * qq.y + nn.z * qq.z + nn.w * qq.w;
        }
        for (int off = 32; off; off >>= 1) acc += __shfl_down(acc, off, 64);
        if (lane == 0) pred[wid] = acc;
        __syncthreads();
        if (threadIdx.x == 0) {
            float s = pred[0] + pred[1] + pred[2] + pred[3];
            ws[3 * MM + 3] = fmaxf(fabsf(s), 1.0f);
        }
        return;
    }

    __shared__ float sred[4];
    const int row = blockIdx.x;
    const float it  = ws[3 * MM + 0];
    const float ft  = ws[3 * MM + 1];
    const float ivi = it * ws[2 * MM + row];

    const float4* cprow = (const float4*)(cp + (size_t)row * MM);
    const float4* kv4   = (const float4*)(ws + MM);
    const float4* qv4   = (const float4*)ws;
    float4*       crow  = (float4*)(C_out + (size_t)row * MM);

    float4 c[4], kk[4], qq[4];
    #pragma unroll
    for (int u = 0; u < 4; ++u) c[u]  = cprow[threadIdx.x + 256 * u];
    #pragma unroll
    for (int u = 0; u < 4; ++u) kk[u] = kv4[threadIdx.x + 256 * u];
    #pragma unroll
    for (int u = 0; u < 4; ++u) qq[u] = qv4[threadIdx.x + 256 * u];

    float acc = 0.f;
    #pragma unroll
    for (int u = 0; u < 4; ++u) {
        float4 o;
        o.x = fmaf(ivi, kk[u].x, ft * c[u].x);
        o.y = fmaf(ivi, kk[u].y, ft * c[u].y);
        o.z = fmaf(ivi, kk[u].z, ft * c[u].z);
        o.w = fmaf(ivi, kk[u].w, ft * c[u].w);
        floatx4 ov = { o.x, o.y, o.z, o.w };
        __builtin_nontemporal_store(ov, (floatx4*)(crow + threadIdx.x + 256 * u));
        acc += o.x * qq[u].x + o.y * qq[u].y + o.z * qq[u].z + o.w * qq[u].w;
    }
    for (int off = 32; off; off >>= 1) acc += __shfl_down(acc, off, 64);
    if (lane == 0) sred[wid] = acc;
    __syncthreads();
    if (threadIdx.x == 0)
        ws[4 * MM + row] = sred[0] + sred[1] + sred[2] + sred[3];
}

// ---------------- K3: ht = ot * num / denom ----------------
__global__ __launch_bounds__(256) void k3_finalize(
    const float* __restrict__ ws, float* __restrict__ ht_out)
{
    const float ot    = ws[3 * MM + 2];
    const float denom = ws[3 * MM + 3];
    const int i = blockIdx.x * 256 + threadIdx.x;
    ht_out[i] = ot * (ws[4 * MM + i] / denom);
}

extern "C" void kernel_launch(void* const* d_in, const int* in_sizes, int n_in,
                              void* d_out, int out_size, void* d_ws, size_t ws_size,
                              hipStream_t stream)
{
    const float* x      = (const float*)d_in[0];
    const float* cp     = (const float*)d_in[1];
    const float* n_prev = (const float*)d_in[2];
    const float* Wq = (const float*)d_in[3];
    const float* bq = (const float*)d_in[4];
    const float* Wk = (const float*)d_in[5];
    const float* bk = (const float*)d_in[6];
    const float* Wv = (const float*)d_in[7];
    const float* bV = (const float*)d_in[8];
    const float* Wi = (const float*)d_in[9];
    const float* bi = (const float*)d_in[10];
    const float* Wf = (const float*)d_in[11];
    const float* bf = (const float*)d_in[12];
    const float* Wo = (const float*)d_in[13];
    const float* bo = (const float*)d_in[14];

    float* out = (float*)d_out;
    float* ht  = out;                        // (M,1)
    float* C   = out + MM;                   // (M,M)
    float* n   = out + MM + (size_t)MM * MM; // (M,1)
    float* ws  = (float*)d_ws;

    k1_gemv_gates<<<1027, 256, 0, stream>>>(x, Wq, bq, Wk, bk, Wv, bV,
                                            Wi, bi, Wf, bf, Wo, bo, ws);
    k2_rowC      <<<MM + 1, 256, 0, stream>>>(cp, n_prev, ws, C, n);
    k3_finalize  <<<MM / 256, 256, 0, stream>>>(ws, ht);
}